// Round 13
// baseline (465.259 us; speedup 1.0000x reference)
//
#include <hip/hip_runtime.h>

#define D64 64
#define EPS 1e-16f

typedef unsigned int uint;
typedef uint uivec2 __attribute__((ext_vector_type(2)));

__device__ __forceinline__ float bf_lo(uint u) { return __uint_as_float(u << 16); }
__device__ __forceinline__ float bf_hi(uint u) { return __uint_as_float(u & 0xffff0000u); }
__device__ __forceinline__ unsigned short f2bf(float f) {
    uint u = __float_as_uint(f);
    u += 0x7fffu + ((u >> 16) & 1u);     // round-to-nearest-even
    return (unsigned short)(u >> 16);
}
__device__ __forceinline__ float rsum16(float p) {
    p += __shfl_xor(p, 1);
    p += __shfl_xor(p, 2);
    p += __shfl_xor(p, 4);
    p += __shfl_xor(p, 8);
    return p;
}
__device__ __forceinline__ float dotk(float4 q4, uivec2 w) {
    return q4.x * bf_lo(w[0]) + q4.y * bf_hi(w[0]) +
           q4.z * bf_lo(w[1]) + q4.w * bf_hi(w[1]);
}

// ---- kernel 1: q,skip f32 + separate bf16 k,v buffers ; fused histogram ----
__global__ __launch_bounds__(256) void qkvs_kernel(
    const float* __restrict__ x,
    const float* __restrict__ Wq, const float* __restrict__ bq,
    const float* __restrict__ Wk, const float* __restrict__ bk,
    const float* __restrict__ Wv, const float* __restrict__ bv,
    const float* __restrict__ Ws, const float* __restrict__ bs,
    float* __restrict__ q, unsigned short* __restrict__ kbuf,
    unsigned short* __restrict__ vbuf,
    float* __restrict__ skip, int n_nodes,
    const int* __restrict__ dst, int* __restrict__ deg, int E)
{
    __shared__ float wq[4096], wk[4096], wv[4096];
    __shared__ float xs[16 * 64];
    __shared__ float bqs[64], bks[64], bvs[64], bss[64];
    int t = threadIdx.x;
    for (int i = t; i < 1024; i += 256) {
        ((float4*)wq)[i] = ((const float4*)Wq)[i];
        ((float4*)wk)[i] = ((const float4*)Wk)[i];
        ((float4*)wv)[i] = ((const float4*)Wv)[i];
    }
    if (t < 64) { bqs[t] = bq[t]; bks[t] = bk[t]; bvs[t] = bv[t]; bss[t] = bs[t]; }
    __syncthreads();

    int d  = t & 63;
    int j0 = t >> 6;
    int ntiles = (n_nodes + 15) / 16;
    for (int tile = blockIdx.x; tile < ntiles; tile += gridDim.x) {
        int base = tile * 16;
        __syncthreads();
        if (base + 16 <= n_nodes) {
            ((float4*)xs)[t] = ((const float4*)x)[(size_t)base * 16 + t];
        } else {
            for (int i = t; i < 1024; i += 256) {
                int node = base + (i >> 6);
                xs[i] = (node < n_nodes) ? x[(size_t)node * 64 + (i & 63)] : 0.0f;
            }
        }
        __syncthreads();

        float aq[4], ak[4], av[4], asv[4];
        #pragma unroll
        for (int j = 0; j < 4; ++j) { aq[j] = bqs[d]; ak[j] = bks[d]; av[j] = bvs[d]; asv[j] = bss[d]; }
        #pragma unroll 8
        for (int i = 0; i < 64; ++i) {
            float w0 = wq[i * 64 + d];
            float w1 = wk[i * 64 + d];
            float w2 = wv[i * 64 + d];
            float w3 = Ws[i * 64 + d];
            #pragma unroll
            for (int j = 0; j < 4; ++j) {
                float xi = xs[(j0 * 4 + j) * 64 + i];
                aq[j]  += xi * w0;
                ak[j]  += xi * w1;
                av[j]  += xi * w2;
                asv[j] += xi * w3;
            }
        }
        #pragma unroll
        for (int j = 0; j < 4; ++j) {
            int node = base + j0 * 4 + j;
            if (node < n_nodes) {
                size_t o = (size_t)node * 64 + d;
                q[o]    = aq[j];
                skip[o] = asv[j];
                kbuf[o] = f2bf(ak[j]);
                vbuf[o] = f2bf(av[j]);
            }
        }
    }

    for (int e = blockIdx.x * 256 + t; e < E; e += gridDim.x * 256)
        atomicAdd(deg + dst[e], 1);
}

// ---- kernel 2: exclusive prefix sum ----
__global__ __launch_bounds__(1024) void scan_kernel(
    const int* __restrict__ deg, int* __restrict__ rowstart, int N, int E)
{
    __shared__ int sums[1024];
    int t = threadIdx.x;
    int chunk = (N + 1023) >> 10;
    int beg = t * chunk;
    int end = min(beg + chunk, N);
    int s = 0;
    for (int i = beg; i < end; ++i) s += deg[i];
    sums[t] = s;
    __syncthreads();
    for (int off = 1; off < 1024; off <<= 1) {
        int add = (t >= off) ? sums[t - off] : 0;
        __syncthreads();
        sums[t] += add;
        __syncthreads();
    }
    int prefix = (t == 0) ? 0 : sums[t - 1];
    for (int i = beg; i < end; ++i) { rowstart[i] = prefix; prefix += deg[i]; }
    if (t == 0) rowstart[N] = E;
}

// ---- kernel 3: CSR fill ----
__global__ __launch_bounds__(256) void fill_kernel(
    const int* __restrict__ src, const int* __restrict__ dst,
    const int* __restrict__ rowstart, int* __restrict__ cursor,
    int* __restrict__ srcs, int E)
{
    int e = blockIdx.x * 256 + threadIdx.x;
    if (e >= E) return;
    int d = dst[e];
    int pos = rowstart[d] + atomicAdd(cursor + d, 1);
    srcs[pos] = src[e];
}

// ---- kernel 4 (pass A): k-gather -> logits, m, den ----
__global__ __launch_bounds__(256) void qk_logits_kernel(
    const float* __restrict__ q, const uint* __restrict__ kbuf,
    const int* __restrict__ rowstart, const int* __restrict__ srcs,
    float* __restrict__ logits, float* __restrict__ mden, int N)
{
    int t = threadIdx.x;
    int l = t & 15;
    int node = (blockIdx.x * 256 + t) >> 4;
    bool valid = node < N;

    float4 q4 = make_float4(0.f, 0.f, 0.f, 0.f);
    int p0 = 0, p1 = 0;
    if (valid) {
        q4 = ((const float4*)q)[(size_t)node * 16 + l];
        p0 = rowstart[node];
        p1 = rowstart[node + 1];
    }

    float m = -INFINITY, den = 0.f;
    const uivec2* k2 = (const uivec2*)kbuf;

    int p = p0;
    for (; p + 4 <= p1; p += 4) {
        int s0 = srcs[p + 0]; int s1 = srcs[p + 1];
        int s2 = srcs[p + 2]; int s3 = srcs[p + 3];
        uivec2 w0 = k2[(size_t)s0 * 16 + l];
        uivec2 w1 = k2[(size_t)s1 * 16 + l];
        uivec2 w2 = k2[(size_t)s2 * 16 + l];
        uivec2 w3 = k2[(size_t)s3 * 16 + l];
        float l0 = rsum16(dotk(q4, w0)) * 0.125f;
        float l1 = rsum16(dotk(q4, w1)) * 0.125f;
        float l2 = rsum16(dotk(q4, w2)) * 0.125f;
        float l3 = rsum16(dotk(q4, w3)) * 0.125f;
        float mx = fmaxf(fmaxf(l0, l1), fmaxf(l2, l3));
        if (mx > m) {
            den *= __expf(m - mx);
            m = mx;
        }
        den += __expf(l0 - m) + __expf(l1 - m) + __expf(l2 - m) + __expf(l3 - m);
        if (l < 4) {
            float lv = (l == 0) ? l0 : (l == 1) ? l1 : (l == 2) ? l2 : l3;
            logits[p + l] = lv;
        }
    }
    for (; p < p1; ++p) {
        int s = srcs[p];
        uivec2 w0 = k2[(size_t)s * 16 + l];
        float lg = rsum16(dotk(q4, w0)) * 0.125f;
        if (lg > m) {
            den *= __expf(m - lg);
            m = lg;
        }
        den += __expf(lg - m);
        if (l == 0) logits[p] = lg;
    }

    if (valid && l == 0) {
        mden[2 * (size_t)node + 0] = m;
        mden[2 * (size_t)node + 1] = den;
    }
}

// ---- kernel 5 (pass B): v-gather -> out, pool ----
__global__ __launch_bounds__(256) void pv_kernel(
    const uint* __restrict__ vbuf, const float* __restrict__ skip,
    const float* __restrict__ logits, const float* __restrict__ mden,
    const int* __restrict__ rowstart, const int* __restrict__ srcs,
    const int* __restrict__ batch,
    float* __restrict__ out, float* __restrict__ cnt, int N)
{
    int t = threadIdx.x;
    int l = t & 15;
    int node = (blockIdx.x * 256 + t) >> 4;
    bool valid = node < N;

    int p0 = 0, p1 = 0;
    float m = 0.f, den = 0.f;
    if (valid) {
        p0 = rowstart[node];
        p1 = rowstart[node + 1];
        m   = mden[2 * (size_t)node + 0];
        den = mden[2 * (size_t)node + 1];
    }

    float4 acc = make_float4(0.f, 0.f, 0.f, 0.f);
    const uivec2* v2 = (const uivec2*)vbuf;

    int p = p0;
    for (; p + 4 <= p1; p += 4) {
        int s0 = srcs[p + 0]; int s1 = srcs[p + 1];
        int s2 = srcs[p + 2]; int s3 = srcs[p + 3];
        uivec2 w0 = v2[(size_t)s0 * 16 + l];
        uivec2 w1 = v2[(size_t)s1 * 16 + l];
        uivec2 w2 = v2[(size_t)s2 * 16 + l];
        uivec2 w3 = v2[(size_t)s3 * 16 + l];
        float e0 = __expf(logits[p + 0] - m);
        float e1 = __expf(logits[p + 1] - m);
        float e2 = __expf(logits[p + 2] - m);
        float e3 = __expf(logits[p + 3] - m);
        acc.x += e0 * bf_lo(w0[0]) + e1 * bf_lo(w1[0]) + e2 * bf_lo(w2[0]) + e3 * bf_lo(w3[0]);
        acc.y += e0 * bf_hi(w0[0]) + e1 * bf_hi(w1[0]) + e2 * bf_hi(w2[0]) + e3 * bf_hi(w3[0]);
        acc.z += e0 * bf_lo(w0[1]) + e1 * bf_lo(w1[1]) + e2 * bf_lo(w2[1]) + e3 * bf_lo(w3[1]);
        acc.w += e0 * bf_hi(w0[1]) + e1 * bf_hi(w1[1]) + e2 * bf_hi(w2[1]) + e3 * bf_hi(w3[1]);
    }
    for (; p < p1; ++p) {
        int s = srcs[p];
        uivec2 w0 = v2[(size_t)s * 16 + l];
        float ev = __expf(logits[p] - m);
        acc.x += ev * bf_lo(w0[0]);
        acc.y += ev * bf_hi(w0[0]);
        acc.z += ev * bf_lo(w0[1]);
        acc.w += ev * bf_hi(w0[1]);
    }

    float4 val = make_float4(0.f, 0.f, 0.f, 0.f);
    int g = -1;
    if (valid) {
        float inv = 1.0f / (den + EPS);
        float4 sk = ((const float4*)skip)[(size_t)node * 16 + l];
        val.x = fmaxf(acc.x * inv + sk.x, 0.f);
        val.y = fmaxf(acc.y * inv + sk.y, 0.f);
        val.z = fmaxf(acc.z * inv + sk.z, 0.f);
        val.w = fmaxf(acc.w * inv + sk.w, 0.f);
        g = batch[node];
    }

    int g0 = __shfl(g, 0);
    bool uni = __all(g == g0);
    if (uni) {
        if (g0 >= 0) {
            val.x += __shfl_xor(val.x, 16); val.x += __shfl_xor(val.x, 32);
            val.y += __shfl_xor(val.y, 16); val.y += __shfl_xor(val.y, 32);
            val.z += __shfl_xor(val.z, 16); val.z += __shfl_xor(val.z, 32);
            val.w += __shfl_xor(val.w, 16); val.w += __shfl_xor(val.w, 32);
            if ((t & 63) < 16) {
                float* o = out + (size_t)g0 * 64 + l * 4;
                atomicAdd(o + 0, val.x);
                atomicAdd(o + 1, val.y);
                atomicAdd(o + 2, val.z);
                atomicAdd(o + 3, val.w);
            }
            if ((t & 63) == 0) atomicAdd(cnt + g0, 4.0f);
        }
    } else if (valid) {
        float* o = out + (size_t)g * 64 + l * 4;
        atomicAdd(o + 0, val.x);
        atomicAdd(o + 1, val.y);
        atomicAdd(o + 2, val.z);
        atomicAdd(o + 3, val.w);
        if (l == 0) atomicAdd(cnt + g, 1.0f);
    }
}

// ---- kernel 6: divide pooled sums ----
__global__ __launch_bounds__(256) void pool_div_kernel(
    float* __restrict__ out, const float* __restrict__ cnt, int n)
{
    int idx = blockIdx.x * 256 + threadIdx.x;
    if (idx >= n) return;
    int g = idx >> 6;
    out[idx] /= fmaxf(cnt[g], 1.0f);
}

// ==== ABLATION A: pv structure, GATHER ONLY (x3 repeats for amplification) ====
// CSR loop + srcs loads + v-row gathers + int accumulate. No logits/exp/FMA.
__global__ __launch_bounds__(256) void abl_gather_kernel(
    const uint* __restrict__ vbuf, const int* __restrict__ rowstart,
    const int* __restrict__ srcs, uint* __restrict__ scratch, int N)
{
    int t = threadIdx.x;
    int l = t & 15;
    int node = (blockIdx.x * 256 + t) >> 4;
    if (node >= N) return;
    int p0 = rowstart[node], p1 = rowstart[node + 1];
    const uivec2* v2 = (const uivec2*)vbuf;
    uint a0 = 0, a1 = 0;
    for (int r = 0; r < 3; ++r) {
        int p = p0;
        for (; p + 4 <= p1; p += 4) {
            int s0 = srcs[p + 0]; int s1 = srcs[p + 1];
            int s2 = srcs[p + 2]; int s3 = srcs[p + 3];
            uivec2 w0 = v2[(size_t)s0 * 16 + l];
            uivec2 w1 = v2[(size_t)s1 * 16 + l];
            uivec2 w2 = v2[(size_t)s2 * 16 + l];
            uivec2 w3 = v2[(size_t)s3 * 16 + l];
            a0 += w0[0] + w1[0] + w2[0] + w3[0];
            a1 += w0[1] + w1[1] + w2[1] + w3[1];
        }
        for (; p < p1; ++p) {
            uivec2 w = v2[(size_t)srcs[p] * 16 + l];
            a0 += w[0]; a1 += w[1];
        }
        a0 = (a0 << 1) | (a0 >> 31);   // make repeats non-foldable
    }
    scratch[(size_t)node * 16 + l] = a0 ^ a1;
}

// ==== ABLATION B: pv structure, STREAM+COMPUTE ONLY (x3 repeats) ====
// CSR loop + srcs/logits loads + exp + 16 FMAs on synthetic values. No v gather.
__global__ __launch_bounds__(256) void abl_compute_kernel(
    const float* __restrict__ logits, const float* __restrict__ mden,
    const int* __restrict__ rowstart, const int* __restrict__ srcs,
    float* __restrict__ scratch, int N)
{
    int t = threadIdx.x;
    int l = t & 15;
    int node = (blockIdx.x * 256 + t) >> 4;
    if (node >= N) return;
    int p0 = rowstart[node], p1 = rowstart[node + 1];
    float m = mden[2 * (size_t)node + 0];
    float den = mden[2 * (size_t)node + 1];
    float4 acc = make_float4(0.f, 0.f, 0.f, 0.f);
    for (int r = 0; r < 3; ++r) {
        int p = p0;
        for (; p + 4 <= p1; p += 4) {
            int s0 = srcs[p + 0]; int s1 = srcs[p + 1];
            int s2 = srcs[p + 2]; int s3 = srcs[p + 3];
            float e0 = __expf(logits[p + 0] - m);
            float e1 = __expf(logits[p + 1] - m);
            float e2 = __expf(logits[p + 2] - m);
            float e3 = __expf(logits[p + 3] - m);
            float h0 = (float)(s0 & 0xffff);
            float h1 = (float)(s1 & 0xffff);
            float h2 = (float)(s2 & 0xffff);
            float h3 = (float)(s3 & 0xffff);
            acc.x += e0 * h0 + e1 * h1 + e2 * h2 + e3 * h3;
            acc.y += e0 * h1 + e1 * h2 + e2 * h3 + e3 * h0;
            acc.z += e0 * h2 + e1 * h3 + e2 * h0 + e3 * h1;
            acc.w += e0 * h3 + e1 * h0 + e2 * h1 + e3 * h2;
        }
        for (; p < p1; ++p) {
            float ev = __expf(logits[p] - m);
            float h = (float)(srcs[p] & 0xffff);
            acc.x += ev * h; acc.y += ev * h * 0.5f;
            acc.z += ev * h * 0.25f; acc.w += ev * h * 0.125f;
        }
        acc.x *= 0.25f; acc.y *= 0.25f; acc.z *= 0.25f; acc.w *= 0.25f;
    }
    scratch[(size_t)node * 16 + l] =
        (acc.x + acc.y + acc.z + acc.w) / (den + EPS);
}

extern "C" void kernel_launch(void* const* d_in, const int* in_sizes, int n_in,
                              void* d_out, int out_size, void* d_ws, size_t ws_size,
                              hipStream_t stream) {
    const float* x     = (const float*)d_in[0];
    const int*   eidx  = (const int*)d_in[1];
    const int*   batch = (const int*)d_in[2];
    const float* Wq = (const float*)d_in[3];
    const float* bq = (const float*)d_in[4];
    const float* Wk = (const float*)d_in[5];
    const float* bk = (const float*)d_in[6];
    const float* Wv = (const float*)d_in[7];
    const float* bv = (const float*)d_in[8];
    const float* Ws = (const float*)d_in[9];
    const float* bs = (const float*)d_in[10];

    int N = in_sizes[0] / D64;
    int E = in_sizes[1] / 2;
    const int* src = eidx;
    const int* dst = eidx + E;

    char* w = (char*)d_ws;
    size_t NB = (size_t)N * D64 * sizeof(float);   // 12.8 MB
    float*          q    = (float*)(w);
    float*          skip = (float*)(w + NB);
    unsigned short* kbuf = (unsigned short*)(w + 2 * NB);            // 6.4 MB
    unsigned short* vbuf = (unsigned short*)(w + 2 * NB + NB / 2);   // 6.4 MB
    char* p = w + 3 * NB;
    float* logits   = (float*)p;               p += (size_t)E * 4;
    float* mden     = (float*)p;               p += 2 * (size_t)N * 4;
    int*   deg      = (int*)p;                 p += (size_t)N * 4;
    int*   cursor   = (int*)p;                 p += (size_t)N * 4;
    float* cnt      = (float*)p;               p += 64 * 4;
    int*   rowstart = (int*)p;                 p += (size_t)(N + 1) * 4;
    int*   srcs     = (int*)p;                 p += (size_t)E * 4;
    uint*  abl1     = (uint*)p;                p += (size_t)N * 16 * 4;
    float* abl2     = (float*)p;

    (void)hipMemsetAsync(deg, 0, (2 * (size_t)N + 64) * 4, stream);
    (void)hipMemsetAsync(d_out, 0, (size_t)out_size * sizeof(float), stream);

    qkvs_kernel<<<1024, 256, 0, stream>>>(x, Wq, bq, Wk, bk, Wv, bv, Ws, bs,
                                          q, kbuf, vbuf, skip, N, dst, deg, E);
    scan_kernel<<<1, 1024, 0, stream>>>(deg, rowstart, N, E);
    int blocks_e = (E + 255) / 256;
    fill_kernel<<<blocks_e, 256, 0, stream>>>(src, dst, rowstart, cursor, srcs, E);
    int blocks_g = ((size_t)N * 16 + 255) / 256;
    qk_logits_kernel<<<blocks_g, 256, 0, stream>>>(q, (const uint*)kbuf, rowstart,
                                                   srcs, logits, mden, N);
    pv_kernel<<<blocks_g, 256, 0, stream>>>((const uint*)vbuf, skip, logits, mden,
                                            rowstart, srcs, batch,
                                            (float*)d_out, cnt, N);
    pool_div_kernel<<<(out_size + 255) / 256, 256, 0, stream>>>((float*)d_out,
                                                                (const float*)cnt, out_size);

    // ---- diagnostics (write only to scratch; 3x amplified) ----
    abl_gather_kernel<<<blocks_g, 256, 0, stream>>>((const uint*)vbuf, rowstart,
                                                    srcs, abl1, N);
    abl_compute_kernel<<<blocks_g, 256, 0, stream>>>(logits, mden, rowstart,
                                                     srcs, abl2, N);
}